// Round 16
// baseline (366.968 us; speedup 1.0000x reference)
//
#include <hip/hip_runtime.h>

// ---------------- problem constants ----------------
#define CCH   256
#define HH    96
#define WW    96
#define HO    94
#define LL    8836        // 94*94 patches
#define DD2   1152        // bytes per patch row (fp4: 2304 elems * 0.5 B)
#define LPAD  8960        // 70 * 128 = 35 * 256
#define NPIX  9216        // 96*96

// GEMM: 128x256 block tile, 8 waves (2M x 4N), wave tile 64x64,
// MX-fp4 mfma_scale_f32_32x32x64_f8f6f4 (uniform scales = 1.0).
// K in 18 double-slices of 128 (64 B/row); LDS ring-3 of 24 KB slots.
// 2 blocks/CU; ONE barrier per double-slice; counted vmcnt(3).
#define NTI   70          // M tiles (8960/128)
#define NTJ   35          // N tiles (8960/256)
#define NPH2  18          // 2304/128 double-slices
#define SLTB  24576       // bytes per ring slot (A 8KB + B 16KB)

typedef unsigned char u8;
typedef unsigned int u32;
typedef unsigned long long u64;

using i32x4  = __attribute__((ext_vector_type(4))) int;
using i32x8  = __attribute__((ext_vector_type(8))) int;
using f32x16 = __attribute__((ext_vector_type(16))) float;

// ---------------- workspace layout (bytes) ----------------
#define OFF_BQ    20643840ull
#define OFF_RNB   41287680ull
#define OFF_N2B   41323520ull
#define OFF_W2X   41359360ull
#define OFF_QSA   41395200ull
#define OFF_QSB   41431040ull
#define OFF_COLS  41466880ull
#define OFF_SAF   41502720ull
#define OFF_P2    41538560ull
#define OFF_PM    41612288ull
#define OFF_BEST  41686016ull

__device__ __forceinline__ void gload16(const void* g, void* l) {
    __builtin_amdgcn_global_load_lds(
        (const __attribute__((address_space(1))) unsigned int*)g,
        (__attribute__((address_space(3))) unsigned int*)l,
        16, 0, 0);
}

// fp4 e2m1 MFMA with uniform unit scales (layout-independent)
__device__ __forceinline__ f32x16 mm_fp4(i32x4 a, i32x4 b, f32x16 c) {
    i32x8 a8 = __builtin_shufflevector(a, a, 0, 1, 2, 3, -1, -1, -1, -1);
    i32x8 b8 = __builtin_shufflevector(b, b, 0, 1, 2, 3, -1, -1, -1, -1);
    return __builtin_amdgcn_mfma_scale_f32_32x32x64_f8f6f4(
        a8, b8, c, 4, 4, 0, 0x7F7F7F7F, 0, 0x7F7F7F7F);
}

// encode |m|<=6 to fp4 e2m1 nibble code (round-to-nearest)
__device__ __forceinline__ u32 fp4enc(float m) {
    float am = fabsf(m);
    int c = am < 1.75f ? (int)(am * 2.f + 0.5f)
                       : (am < 2.5f ? 4 : (am < 3.5f ? 5 : (am < 5.f ? 6 : 7)));
    return (u32)c | ((__float_as_uint(m) >> 28) & 8u);
}

// ---- 1: per-pixel channel sum-of-squares and abs-max for both images ----
__global__ __launch_bounds__(256) void k_chan_stats(const float* __restrict__ st,
                                                    const float* __restrict__ x,
                                                    float* __restrict__ P2,
                                                    float* __restrict__ PM) {
    __shared__ float s2[8][32], sm[8][32];
    const int pix = threadIdx.x & 31, cg = threadIdx.x >> 5;
    const int pglob = blockIdx.x * 32;
    const bool isX = pglob >= NPIX;
    const float* img = isX ? x : st;
    const int pp = (isX ? pglob - NPIX : pglob) + pix;
    float s = 0.f, m = 0.f;
    const float* base = img + (size_t)(cg * 32) * NPIX + pp;
#pragma unroll 8
    for (int c = 0; c < 32; ++c) {
        float v = base[c * NPIX];
        s += v * v;
        m = fmaxf(m, fabsf(v));
    }
    s2[cg][pix] = s;
    sm[cg][pix] = m;
    __syncthreads();
    if (cg == 0) {
        float S = s, M = m;
#pragma unroll
        for (int g = 1; g < 8; ++g) {
            S += s2[g][pix];
            M = fmaxf(M, sm[g][pix]);
        }
        P2[pglob + pix] = S;
        PM[pglob + pix] = M;
    }
}

// ---- 2: 3x3 window reductions -> norms, fp4 quantizer scales; init ----
__global__ __launch_bounds__(256) void k_win(const float* __restrict__ P2,
                                             const float* __restrict__ PM,
                                             float* __restrict__ rnB,
                                             float* __restrict__ n2B,
                                             float* __restrict__ win2x,
                                             float* __restrict__ qsA,
                                             float* __restrict__ qsB,
                                             float* __restrict__ colS,
                                             float* __restrict__ sAf,
                                             u64* __restrict__ best,
                                             float* __restrict__ out) {
    int i = blockIdx.x * 256 + threadIdx.x;
    if (i >= LL) return;
    if (i == 0) *out = 0.f;
    best[i] = 0;
    int y = i / HO, xc = i % HO;
    float ss = 0.f, sx = 0.f, ms = 0.f, mx = 0.f;
#pragma unroll
    for (int kh = 0; kh < 3; ++kh)
#pragma unroll
        for (int kw = 0; kw < 3; ++kw) {
            int off = (y + kh) * WW + xc + kw;
            ss += P2[off];
            sx += P2[NPIX + off];
            ms = fmaxf(ms, PM[off]);
            mx = fmaxf(mx, PM[NPIX + off]);
        }
    float rn = 1.f / (sqrtf(ss) + 1e-8f);
    float msc = fmaxf(ms, 1e-30f), mxc = fmaxf(mx, 1e-30f);
    rnB[i] = rn;
    n2B[i] = ss;
    win2x[i] = sx;
    qsA[i] = 6.f / mxc;                 // x fp4 quantizer
    qsB[i] = 6.f / msc;                 // style fp4 quantizer
    colS[i] = rn * msc * (1.f / 6.f);   // argmax column scale
    sAf[i] = mxc * (1.f / 6.f);         // row dequant scale
}

// ---- 3: quantize patches to fp4 nibbles, LDS byte-stage + pack on copy ----
__global__ __launch_bounds__(512) void k_pack(const float* __restrict__ x,
                                              const float* __restrict__ st,
                                              const float* __restrict__ qsA,
                                              const float* __restrict__ qsB,
                                              u8* __restrict__ Aq,
                                              u8* __restrict__ Bq) {
    extern __shared__ u8 plds[];   // 47 * 2304 = 108288 bytes (nibble codes)

    const int b = blockIdx.x;
    const int side = b & 1;            // 0 = A (x), 1 = B (style)
    const int half = (b >> 1) & 1;
    const int y = b >> 2;              // 0..93
    const int xc0 = half * 47;

    const float* src = side ? st : x;
    const float* qs  = side ? qsB : qsA;
    u8* dst = (side ? Bq : Aq) + (size_t)(y * HO + xc0) * DD2;

    const int t = threadIdx.x;
    if (t < 47 * 9) {
        const int il = t / 9, k = t - il * 9;
        const int kh = k / 3, kw = k - kh * 3;
        const int i = y * HO + xc0 + il;
        const float scale = qs[i];
        const float* sp = src + (y + kh) * WW + (xc0 + il + kw);
        u8* lp = plds + il * 2304 + k;
#pragma unroll 8
        for (int c = 0; c < CCH; ++c)
            lp[c * 9] = (u8)fp4enc(sp[c * NPIX] * scale);
    }
    __syncthreads();
    // pack pairs of nibble codes -> bytes; 47*1152 B out = 3384 x 16B chunks
    for (int idx = t; idx < 3384; idx += 512) {
        const u32* s = (const u32*)(plds + idx * 32);
        i32x4 o;
#pragma unroll
        for (int qq = 0; qq < 4; ++qq) {
            u32 u0 = s[2 * qq], u1 = s[2 * qq + 1];
            u32 v0 = u0 | (u0 >> 4);
            u32 v1 = u1 | (u1 >> 4);
            o[qq] = (int)((v0 & 0xFFu) | ((v0 >> 8) & 0xFF00u) |
                          ((v1 & 0xFFu) << 16) | (((v1 >> 8) & 0xFF00u) << 16));
        }
        *(i32x4*)(dst + idx * 16) = o;
    }
}

// ---- 4: fused MX-fp4 GEMM (A * B^T) + per-row scaled argmax ----
__global__ __launch_bounds__(512, 4) void k_gemm2(const u8* __restrict__ A,
                                                  const u8* __restrict__ Bm,
                                                  const float* __restrict__ colS,
                                                  u64* __restrict__ best) {
    extern __shared__ __align__(16) u8 lds[];  // 3 x 24576 = 73728 B

    const int t = threadIdx.x;
    const int wid = t >> 6, lane = t & 63;
    const int wr = wid >> 2, wc = wid & 3;
    const int l31 = lane & 31, lh = lane >> 5;

    // T1: bijective XCD swizzle (m204), nwg = 2450 (q=306, r=2)
    const int nwg = NTI * NTJ;
    const int q = nwg >> 3, r = nwg & 7;
    const int bid = blockIdx.x;
    const int xcd = bid & 7, loc = bid >> 3;
    const int swz = ((xcd < r) ? xcd * (q + 1) : r * (q + 1) + (xcd - r) * q) + loc;
    const int it = swz / NTJ, jt = swz % NTJ;

    // staging sources: LDS layout per slot:
    //   A: [sub:2][kh:2][row:128] x 16B   (8 KB)
    //   B: +8192, [sub:2][kh:2][row:256] x 16B  (16 KB)
    // thread t stages 3 chunks (all linear: dst = slot + t*16 + j*8192)
    const u8* srcA0 = A + (size_t)(it * 128 + (t & 127)) * DD2
                        + ((t >> 8) & 1) * 32 + ((t >> 7) & 1) * 16;
    const u8* srcB0 = Bm + (size_t)(jt * 256 + (t & 255)) * DD2
                         + ((t >> 8) & 1) * 16;
    const u8* srcB1 = srcB0 + 32;

    // fragment read offsets (block-LDS-relative bytes), per sub s:
    int aoff[2][2], boff[2][2];
#pragma unroll
    for (int s = 0; s < 2; ++s) {
#pragma unroll
        for (int mi = 0; mi < 2; ++mi)
            aoff[s][mi] = s * 4096 + lh * 2048 + (wr * 64 + mi * 32 + l31) * 16;
#pragma unroll
        for (int ni = 0; ni < 2; ++ni)
            boff[s][ni] = 8192 + s * 8192 + lh * 4096 + (wc * 64 + ni * 32 + l31) * 16;
    }

    f32x16 acc[2][2];
#pragma unroll
    for (int mi = 0; mi < 2; ++mi)
#pragma unroll
        for (int ni = 0; ni < 2; ++ni)
#pragma unroll
            for (int e = 0; e < 16; ++e)
                acc[mi][ni][e] = 0.f;

#define STAGE(SS, SP)                                                        \
    do {                                                                     \
        const size_t kb = (size_t)(((SS) > NPH2 - 1) ? (NPH2 - 1) : (SS)) * 64; \
        u8* d = lds + (SP) * SLTB + t * 16;                                  \
        gload16(srcA0 + kb, d);                                              \
        gload16(srcB0 + kb, d + 8192);                                       \
        gload16(srcB1 + kb, d + 16384);                                      \
    } while (0)

    // prologue: stage double-slices 0,1; wait slice 0 (slice 1 in flight)
    STAGE(0, 0);
    STAGE(1, 1);
    asm volatile("s_waitcnt vmcnt(3)" ::: "memory");
    __builtin_amdgcn_sched_barrier(0);
    __builtin_amdgcn_s_barrier();

// BODY(S,SC): one barrier per double-slice. 8 frag reads + stage S+2 +
// 8 MFMA (2 subs x 2x2); lgkm(0) before MFMA; vmcnt(3) after; barrier.
#define BODY(S, SC)                                                          \
    {                                                                        \
        const u8* sb = lds + (SC) * SLTB;                                    \
        i32x4 a00 = *(const i32x4*)(sb + aoff[0][0]);                        \
        i32x4 a01 = *(const i32x4*)(sb + aoff[0][1]);                        \
        i32x4 b00 = *(const i32x4*)(sb + boff[0][0]);                        \
        i32x4 b01 = *(const i32x4*)(sb + boff[0][1]);                        \
        i32x4 a10 = *(const i32x4*)(sb + aoff[1][0]);                        \
        i32x4 a11 = *(const i32x4*)(sb + aoff[1][1]);                        \
        i32x4 b10 = *(const i32x4*)(sb + boff[1][0]);                        \
        i32x4 b11 = *(const i32x4*)(sb + boff[1][1]);                        \
        STAGE((S) + 2, ((SC) + 2) % 3);                                      \
        asm volatile("s_waitcnt lgkmcnt(0)" ::: "memory");                   \
        __builtin_amdgcn_sched_barrier(0);                                   \
        __builtin_amdgcn_s_setprio(1);                                       \
        acc[0][0] = mm_fp4(a00, b00, acc[0][0]);                             \
        acc[0][1] = mm_fp4(a00, b01, acc[0][1]);                             \
        acc[1][0] = mm_fp4(a01, b00, acc[1][0]);                             \
        acc[1][1] = mm_fp4(a01, b01, acc[1][1]);                             \
        acc[0][0] = mm_fp4(a10, b10, acc[0][0]);                             \
        acc[0][1] = mm_fp4(a10, b11, acc[0][1]);                             \
        acc[1][0] = mm_fp4(a11, b10, acc[1][0]);                             \
        acc[1][1] = mm_fp4(a11, b11, acc[1][1]);                             \
        __builtin_amdgcn_s_setprio(0);                                       \
        asm volatile("s_waitcnt vmcnt(3)" ::: "memory");                     \
        __builtin_amdgcn_sched_barrier(0);                                   \
        __builtin_amdgcn_s_barrier();                                        \
    }

    for (int s3 = 0; s3 < NPH2; s3 += 3) {
        BODY(s3,     0)
        BODY(s3 + 1, 1)
        BODY(s3 + 2, 2)
    }
#undef BODY
#undef STAGE

    // epilogue: 32x32 C/D layout: row=(reg&3)+8*(reg>>2)+4*lh, col=l31.
    const int jbase = jt * 256 + wc * 64 + l31;
    float cs[2];
#pragma unroll
    for (int ni = 0; ni < 2; ++ni) {
        int j = jbase + ni * 32;
        cs[ni] = colS[j < LL ? j : 0];
    }
#pragma unroll
    for (int mi = 0; mi < 2; ++mi) {
#pragma unroll
        for (int reg = 0; reg < 16; ++reg) {
            float bv = -3.4e38f;
            int bj = 0x7FFFFFFF;
#pragma unroll
            for (int ni = 0; ni < 2; ++ni) {
                int j = jbase + ni * 32;
                float v = acc[mi][ni][reg] * cs[ni];
                if (j < LL && (v > bv || (v == bv && j < bj))) { bv = v; bj = j; }
            }
#pragma unroll
            for (int m = 1; m < 32; m <<= 1) {
                float ov = __shfl_xor(bv, m, 64);
                int oj = __shfl_xor(bj, m, 64);
                if (ov > bv || (ov == bv && oj < bj)) { bv = ov; bj = oj; }
            }
            if (l31 == 0) {
                int i = it * 128 + wr * 64 + mi * 32 + (reg & 3) + 8 * (reg >> 2) + 4 * lh;
                if (i < LL) {
                    unsigned u = __float_as_uint(bv);
                    unsigned s = (bv < 0.f) ? ~u : (u | 0x80000000u);
                    u64 packed = ((u64)s << 32) | (unsigned)(~(unsigned)bj);
                    atomicMax(&best[i], packed);
                }
            }
        }
    }
}

// ---- 5: final scalar ----
__global__ __launch_bounds__(256) void k_final(const u64* __restrict__ best,
                                               const float* __restrict__ rnB,
                                               const float* __restrict__ n2B,
                                               const float* __restrict__ win2x,
                                               const float* __restrict__ sAf,
                                               float* __restrict__ out) {
    int i = blockIdx.x * 256 + threadIdx.x;
    float contrib = 0.f;
    if (i < LL) {
        u64 p = best[i];
        unsigned s = (unsigned)(p >> 32);
        unsigned ub = (s & 0x80000000u) ? (s & 0x7FFFFFFFu) : ~s;
        float bv = __uint_as_float(ub);
        int j = (int)(~(unsigned)(p & 0xFFFFFFFFull));
        float dot = (bv * sAf[i]) / rnB[j];
        contrib = win2x[i] + n2B[j] - 2.f * dot;
    }
    float sred = contrib;
#pragma unroll
    for (int o = 32; o > 0; o >>= 1) sred += __shfl_down(sred, o, 64);
    __shared__ float red[4];
    if ((threadIdx.x & 63) == 0) red[threadIdx.x >> 6] = sred;
    __syncthreads();
    if (threadIdx.x == 0) {
        float tot = red[0] + red[1] + red[2] + red[3];
        atomicAdd(out, tot * (1.0f / (2304.f * (float)LL)));
    }
}

extern "C" void kernel_launch(void* const* d_in, const int* in_sizes, int n_in,
                              void* d_out, int out_size, void* d_ws, size_t ws_size,
                              hipStream_t stream) {
    const float* x  = (const float*)d_in[0];
    const float* st = (const float*)d_in[1];
    char* ws = (char*)d_ws;

    u8* Aq       = (u8*)ws;
    u8* Bq       = (u8*)(ws + OFF_BQ);
    float* rnB   = (float*)(ws + OFF_RNB);
    float* n2B   = (float*)(ws + OFF_N2B);
    float* win2x = (float*)(ws + OFF_W2X);
    float* qsA   = (float*)(ws + OFF_QSA);
    float* qsB   = (float*)(ws + OFF_QSB);
    float* colS  = (float*)(ws + OFF_COLS);
    float* sAf   = (float*)(ws + OFF_SAF);
    float* P2    = (float*)(ws + OFF_P2);
    float* PM    = (float*)(ws + OFF_PM);
    u64* best    = (u64*)(ws + OFF_BEST);
    float* out   = (float*)d_out;

    hipFuncSetAttribute((const void*)k_gemm2,
                        hipFuncAttributeMaxDynamicSharedMemorySize, 73728);
    hipFuncSetAttribute((const void*)k_pack,
                        hipFuncAttributeMaxDynamicSharedMemorySize, 110592);

    k_chan_stats<<<dim3(2 * NPIX / 32), dim3(256), 0, stream>>>(st, x, P2, PM);
    k_win<<<dim3(35), dim3(256), 0, stream>>>(P2, PM, rnB, n2B, win2x,
                                              qsA, qsB, colS, sAf, best, out);
    k_pack<<<dim3(HO * 4), dim3(512), 108288, stream>>>(x, st, qsA, qsB, Aq, Bq);
    k_gemm2<<<dim3(NTI * NTJ), dim3(512), 73728, stream>>>(Aq, Bq, colS, best);
    k_final<<<dim3(35), dim3(256), 0, stream>>>(best, rnB, n2B, win2x, sAf, out);
}